// Round 1
// baseline (291.837 us; speedup 1.0000x reference)
//
#include <hip/hip_runtime.h>

// DeformedAgent reduced form (see analysis):
//   idx[b,j] == j for all finite inputs (tanh-bounded offset < 0.016 around j+0.5)
//   frac == 0 exactly (4095/63 == 65 exact in f32)
// =>  out[(b*64+j)*1024 + c] = bq[c] + sum_{c2} wq[c*1024+c2] * G[b,j,c2]
//     G[b,j,c2] = tokens[b*4097*1024 + 1024 + j*65536 + ((c2>>6)<<12) + 65*(c2&63)]
// Output flat layout (B*H, HD, LK) == flat (B, LK, C)  (pure reshape).

#define C_   1024
#define TOK_STRIDE (4097 * 1024)
#define TILE_R 16
#define TILE_C 128
#define NT   256

__global__ __launch_bounds__(NT, 2)
void da_gemm_kernel(const float* __restrict__ tokens,
                    const float* __restrict__ wq,
                    const float* __restrict__ bq,
                    float* __restrict__ out) {
    __shared__ float Gt[TILE_R][C_];   // 64 KB -> 2 blocks/CU

    const int tid = threadIdx.x;
    const int r0  = blockIdx.x * TILE_R;   // 32 row tiles (512 rows total)
    const int c0  = blockIdx.y * TILE_C;   // 8 col tiles (1024 cols total)

    // ---- gather stage: TILE_R*1024 = 16384 elements, 64 per thread ----
    #pragma unroll 4
    for (int it = 0; it < (TILE_R * C_) / NT; ++it) {
        int idx = it * NT + tid;
        int rr  = idx >> 10;          // row within tile
        int c2  = idx & 1023;         // k index
        int r   = r0 + rr;
        int b   = r >> 6;
        int j   = r & 63;
        Gt[rr][c2] = tokens[b * TOK_STRIDE + 1024 + (j << 16)
                            + ((c2 >> 6) << 12) + 65 * (c2 & 63)];
    }
    __syncthreads();

    // ---- compute: each thread owns 1 col x 8 rows ----
    const int c  = c0 + (tid & 127);       // 128 cols, 2 threads per col
    const int rh = (tid >> 7) * 8;         // row half: 0 or 8
    const float* __restrict__ wrow = wq + (size_t)c * C_;

    float acc[8];
    #pragma unroll
    for (int i = 0; i < 8; ++i) acc[i] = 0.f;

    #pragma unroll 2
    for (int k = 0; k < C_; k += 4) {
        const float4 w = *reinterpret_cast<const float4*>(wrow + k);
        #pragma unroll
        for (int i = 0; i < 8; ++i) {
            // wave-broadcast LDS read: all 64 lanes in a wave share (rh+i, k)
            const float4 g = *reinterpret_cast<const float4*>(&Gt[rh + i][k]);
            acc[i] += g.x * w.x + g.y * w.y + g.z * w.z + g.w * w.w;
        }
    }

    const float bqc = bq[c];
    #pragma unroll
    for (int i = 0; i < 8; ++i) {
        out[(size_t)(r0 + rh + i) * C_ + c] = acc[i] + bqc;
    }
}

extern "C" void kernel_launch(void* const* d_in, const int* in_sizes, int n_in,
                              void* d_out, int out_size, void* d_ws, size_t ws_size,
                              hipStream_t stream) {
    // inputs: 0=q 1=tokens 2=w_dw 3=b_dw 4=ln_w 5=ln_b 6=w_off 7=wq 8=bq
    const float* tokens = (const float*)d_in[1];
    const float* wq     = (const float*)d_in[7];
    const float* bq     = (const float*)d_in[8];
    float* out          = (float*)d_out;

    dim3 grid(512 / TILE_R, 1024 / TILE_C);   // 32 x 8 = 256 blocks
    da_gemm_kernel<<<grid, NT, 0, stream>>>(tokens, wq, bq, out);
}

// Round 2
// 290.352 us; speedup vs baseline: 1.0051x; 1.0051x over previous
//
#include <hip/hip_runtime.h>

// Reduced form (verified round 1, absmax 7.8e-3):
//   out[(b*64+j)*1024 + c] = bq[c] + sum_{c2} wq[c*1024+c2] * G[b,j,c2]
//   G[b,j,c2] = tokens[b*4097*1024 + 1024 + j*65536 + ((c2>>6)<<12) + 65*(c2&63)]
//
// This round: K-split-4 + atomicAdd, 4x4 register tiling, W staged in LDS.

#define C_        1024
#define TOK_STRIDE (4097 * 1024)
#define TILE_R    32
#define TILE_C    128
#define KSLICE    256
#define KCH       32          // k-chunk staged in Wt per inner iteration
#define NT        256
#define GT_LD     260         // Gt row stride (dwords): 1040B, 16B-aligned, de-conflicts row pairs
#define WT_LD     36          // Wt row stride (dwords): 144B, 16B-aligned, full-BW reads

__global__ __launch_bounds__(NT, 2)
void da_init_out(const float* __restrict__ bq, float* __restrict__ out) {
    // grid 512 = one block per output row; out[r][c] = bq[c]
    const int r = blockIdx.x;
    const int t = threadIdx.x;
    float4 b = reinterpret_cast<const float4*>(bq)[t];
    reinterpret_cast<float4*>(out + (size_t)r * C_)[t] = b;
}

__global__ __launch_bounds__(NT, 2)
void da_gemm(const float* __restrict__ tokens,
             const float* __restrict__ wq,
             float* __restrict__ out) {
    __shared__ float Gt[TILE_R][GT_LD];   // 33.3 KB
    __shared__ float Wt[TILE_C][WT_LD];   // 18.4 KB   -> 51.7 KB total (<64KB static)

    const int t  = threadIdx.x;
    const int r0 = blockIdx.x * TILE_R;
    const int c0 = blockIdx.y * TILE_C;
    const int k0 = blockIdx.z * KSLICE;

    // ---- gather G tile: rows r0..r0+31, k in [k0, k0+256). NT == KSLICE. ----
    {
        const int kk = t;                  // 0..255
        const int c2 = k0 + kk;
        const int base_off = 1024 + ((c2 >> 6) << 12) + 65 * (c2 & 63);
        #pragma unroll 8
        for (int rr = 0; rr < TILE_R; ++rr) {
            const int r = r0 + rr;
            const int b = r >> 6;
            const int j = r & 63;
            Gt[rr][kk] = tokens[(size_t)b * TOK_STRIDE + (j << 16) + base_off];
        }
    }

    const int colv = t & 31;              // lane's base column (stride-32 cols)
    const int rowg = t >> 5;              // row group: 4 rows each

    float acc[4][4];
    #pragma unroll
    for (int i = 0; i < 4; ++i)
        #pragma unroll
        for (int j = 0; j < 4; ++j) acc[i][j] = 0.f;

    for (int ch = 0; ch < KSLICE / KCH; ++ch) {      // 8 chunks
        __syncthreads();   // prev compute done (and, at ch=0, covers nothing yet)
        // ---- stage Wt: 128 cols x 32 k = 1024 float4, 4 per thread, coalesced ----
        #pragma unroll
        for (int i = 0; i < 4; ++i) {
            const int idx4 = t + NT * i;
            const int c    = idx4 >> 3;     // 0..127
            const int kq   = idx4 & 7;      // 0..7
            const float4 w = *reinterpret_cast<const float4*>(
                wq + (size_t)(c0 + c) * C_ + k0 + ch * KCH + kq * 4);
            *reinterpret_cast<float4*>(&Wt[c][kq * 4]) = w;
        }
        __syncthreads();
        // ---- compute: 8 quads x 64 FMAs ----
        #pragma unroll
        for (int q = 0; q < KCH / 4; ++q) {
            float4 g[4], w[4];
            #pragma unroll
            for (int i = 0; i < 4; ++i)
                g[i] = *reinterpret_cast<const float4*>(&Gt[rowg * 4 + i][ch * KCH + q * 4]);
            #pragma unroll
            for (int j = 0; j < 4; ++j)
                w[j] = *reinterpret_cast<const float4*>(&Wt[colv + 32 * j][q * 4]);
            #pragma unroll
            for (int i = 0; i < 4; ++i)
                #pragma unroll
                for (int j = 0; j < 4; ++j)
                    acc[i][j] += g[i].x * w[j].x + g[i].y * w[j].y
                               + g[i].z * w[j].z + g[i].w * w[j].w;
        }
    }

    // ---- epilogue: K-split partial -> atomic accumulate ----
    #pragma unroll
    for (int i = 0; i < 4; ++i) {
        const int r = r0 + rowg * 4 + i;
        #pragma unroll
        for (int j = 0; j < 4; ++j) {
            atomicAdd(&out[(size_t)r * C_ + c0 + colv + 32 * j], acc[i][j]);
        }
    }
}

extern "C" void kernel_launch(void* const* d_in, const int* in_sizes, int n_in,
                              void* d_out, int out_size, void* d_ws, size_t ws_size,
                              hipStream_t stream) {
    // inputs: 0=q 1=tokens 2=w_dw 3=b_dw 4=ln_w 5=ln_b 6=w_off 7=wq 8=bq
    const float* tokens = (const float*)d_in[1];
    const float* wq     = (const float*)d_in[7];
    const float* bq     = (const float*)d_in[8];
    float* out          = (float*)d_out;

    da_init_out<<<512, NT, 0, stream>>>(bq, out);

    dim3 grid(512 / TILE_R, C_ / TILE_C, 1024 / KSLICE);   // 16 x 8 x 4 = 512 blocks
    da_gemm<<<grid, NT, 0, stream>>>(tokens, wq, out);
}